// Round 8
// baseline (279.701 us; speedup 1.0000x reference)
//
#include <hip/hip_runtime.h>
#include <hip/hip_bf16.h>

#define NN 50000
#define NE 1600000
#define D  128

typedef unsigned int u32;
typedef unsigned long long u64;
typedef unsigned short u16;
typedef __attribute__((ext_vector_type(8))) short short8;
typedef __attribute__((ext_vector_type(4))) float f32x4;
typedef __attribute__((ext_vector_type(2))) float f32x2;

// ws layout (bytes):
//   dcnt u32[NN]    @ 0           (200 KB, memset 0)
//   flag int        @ 200000      (memset 0)
//   head u32[NN*8]  @ 200064      (1.6 MB, NO init needed)
//   node u64[NE]    @ 1800064     (12.8 MB)  {src:lo32, next:hi32}
//   xf8  fp8[NN*D]  @ 14600064    (6.4 MB)   e4m3, row = 128 B = 32 dwords
#define DCNT_OFF  0
#define FLAG_OFF  200000
#define HEAD_OFF  200064
#define NODE_OFF  1800064
#define XF8_OFF   14600064

__device__ __forceinline__ u32 pack2(float a, float b) {   // 2x f32 -> bf16 RNE
    u32 ua = __float_as_uint(a), ub = __float_as_uint(b);
    ua = (ua + 0x7FFFu + ((ua >> 16) & 1u)) >> 16;
    ub = (ub + 0x7FFFu + ((ub >> 16) & 1u)) >> 16;
    return ua | (ub << 16);
}

// ---------------------------------------------------------------------------
__global__ __launch_bounds__(256) void k_detect(const int* __restrict__ ei,
                                                int* __restrict__ flag) {
    int local = 0;
    for (int i = threadIdx.x; i < 2048; i += 256)
        if (ei[2 * i + 1] == 0) local++;
    if (local) atomicAdd(flag, local);
}

// ---------------------------------------------------------------------------
// x (f32) -> xf8 (fp8 e4m3, 4/word), coalesced.
__global__ __launch_bounds__(256) void k_cast(const float* __restrict__ x,
                                              uint2* __restrict__ xf8) {
    const int total = NN * D / 8;  // 800000
    for (int i = blockIdx.x * 256 + threadIdx.x; i < total; i += gridDim.x * 256) {
        const float4 a = reinterpret_cast<const float4*>(x)[2 * i];
        const float4 b = reinterpret_cast<const float4*>(x)[2 * i + 1];
        uint2 o;
        o.x = (u32)__builtin_amdgcn_cvt_pk_fp8_f32(a.z, a.w,
                 __builtin_amdgcn_cvt_pk_fp8_f32(a.x, a.y, 0, false), true);
        o.y = (u32)__builtin_amdgcn_cvt_pk_fp8_f32(b.z, b.w,
                 __builtin_amdgcn_cvt_pk_fp8_f32(b.x, b.y, 0, false), true);
        xf8[i] = o;
    }
}

// ---------------------------------------------------------------------------
// Round-robin balanced chains: pos = dcnt[dst]++ ; c = pos&7.
// Chain c of a deg-d node gets exactly (d>>3) + (c < (d&7)) entries.
__global__ __launch_bounds__(256) void k_link(const int* __restrict__ ei,
                                              const int* __restrict__ flag,
                                              u32* __restrict__ dcnt,
                                              u32* __restrict__ head,
                                              u64* __restrict__ node) {
    const bool is64 = (*flag > 1024);
    const int stride = gridDim.x * 256;
    for (int e = blockIdx.x * 256 + threadIdx.x; e < NE; e += stride) {
        int src, dst;
        if (is64) { src = ei[2 * (size_t)e]; dst = ei[2 * (size_t)(NE + e)]; }
        else      { src = ei[e];             dst = ei[NE + e]; }
        const u32 c = atomicAdd(&dcnt[dst], 1u) & 7u;
        const u32 old = atomicExch(&head[dst * 8 + c], (u32)e);
        node[e] = (u64)(u32)src | ((u64)old << 32);
    }
}

// ---------------------------------------------------------------------------
// Gather-reduce: one wave per node, 8 balanced chains, 2 edges per row-load.
// deg known -> `full` iterations are completely check-free; one tail iter.
__global__ __launch_bounds__(256) void k_gather(const u32* __restrict__ xf8,
                                                const u64* __restrict__ node,
                                                const u32* __restrict__ head,
                                                const u32* __restrict__ dcnt,
                                                float* __restrict__ mean) {
    const int lane = threadIdx.x & 63;
    const int half = lane >> 5;       // 0: even chains, 1: odd chains
    const int q    = lane & 31;       // dword slot within row
    const int n = (int)((blockIdx.x * 256u + threadIdx.x) >> 6);
    if (n >= NN) return;

    const int deg  = (int)dcnt[n];
    const int full = deg >> 3;
    const int tail = deg & 7;

    u32 e[8];
    #pragma unroll
    for (int i = 0; i < 8; i++) e[i] = head[n * 8 + i];  // unused entries never walked

    float acc0 = 0.f, acc1 = 0.f, acc2 = 0.f, acc3 = 0.f;

    for (int it = 0; it < full; ++it) {          // all 8 chains provably alive
        u64 nd[8];
        #pragma unroll
        for (int i = 0; i < 8; i++) nd[i] = node[e[i]];
        #pragma unroll
        for (int p = 0; p < 4; p++) {
            const u32 src = half ? (u32)nd[2 * p + 1] : (u32)nd[2 * p];
            const u32 w = xf8[(size_t)src * 32 + q];
            const f32x2 lo = __builtin_amdgcn_cvt_pk_f32_fp8((int)w, false);
            const f32x2 hi = __builtin_amdgcn_cvt_pk_f32_fp8((int)w, true);
            acc0 += lo.x; acc1 += lo.y; acc2 += hi.x; acc3 += hi.y;
        }
        #pragma unroll
        for (int i = 0; i < 8; i++) e[i] = (u32)(nd[i] >> 32);
    }

    if (tail) {                                   // chains c < tail have 1 left
        u64 nd[8];
        #pragma unroll
        for (int i = 0; i < 8; i++) nd[i] = node[(i < tail) ? e[i] : e[0]];
        #pragma unroll
        for (int p = 0; p < 4; p++) {
            const u32 src   = half ? (u32)nd[2 * p + 1] : (u32)nd[2 * p];
            const bool alive = (half ? (2 * p + 1) : (2 * p)) < tail;
            u32 w = xf8[(size_t)src * 32 + q];
            w = alive ? w : 0u;                   // fp8 0x00 == 0.0f
            const f32x2 lo = __builtin_amdgcn_cvt_pk_f32_fp8((int)w, false);
            const f32x2 hi = __builtin_amdgcn_cvt_pk_f32_fp8((int)w, true);
            acc0 += lo.x; acc1 += lo.y; acc2 += hi.x; acc3 += hi.y;
        }
    }

    acc0 += __shfl_xor(acc0, 32);
    acc1 += __shfl_xor(acc1, 32);
    acc2 += __shfl_xor(acc2, 32);
    acc3 += __shfl_xor(acc3, 32);

    const float inv = deg ? 1.0f / (float)deg : 0.0f;
    if (half == 0) {
        float4 r;
        r.x = acc0 * inv; r.y = acc1 * inv; r.z = acc2 * inv; r.w = acc3 * inv;
        *reinterpret_cast<float4*>(mean + (size_t)n * D + q * 4) = r;
    }
}

// ---------------------------------------------------------------------------
// MFMA GEMM: out = relu([mean|x] @ [Wl|Wr]^T + bl), K=256, bf16 in, f32 acc.
// io = d_out: mean rows read into LDS per 16-row group, then overwritten.
__global__ __launch_bounds__(256) void k_gemm(const float* __restrict__ Wl,
                                              const float* __restrict__ Wr,
                                              const float* __restrict__ bl,
                                              const float* __restrict__ x,
                                              float* __restrict__ io) {
    __shared__ u16 Bs[128 * 256];  // [j][k] bf16, byte ^= (j&7)<<4
    __shared__ u16 As[16 * 256];   // [m][k] bf16, byte ^= (m&7)<<4

    const int t = threadIdx.x;

    for (int s = t; s < 4096; s += 256) {
        const int mat = s >> 11;
        const int j   = (s >> 4) & 127;
        const int k8  = (s & 15) * 8;
        const float* src = (mat ? Wr : Wl) + (size_t)j * 128 + k8;
        const float4 a = reinterpret_cast<const float4*>(src)[0];
        const float4 b = reinterpret_cast<const float4*>(src)[1];
        uint4 o;
        o.x = pack2(a.x, a.y); o.y = pack2(a.z, a.w);
        o.z = pack2(b.x, b.y); o.w = pack2(b.z, b.w);
        const u32 byte = ((u32)(j * 512 + (mat * 128 + k8) * 2)) ^ ((u32)(j & 7) << 4);
        *reinterpret_cast<uint4*>(reinterpret_cast<char*>(Bs) + byte) = o;
    }

    const int lane = t & 63;
    const int wv   = t >> 6;
    const int m16  = lane & 15;
    const int kg   = lane >> 4;

    for (int g = blockIdx.x; g < NN / 16; g += gridDim.x) {
        const int row0 = g * 16;
        __syncthreads();
        {
            const int m  = t >> 4;
            const int k8 = (t & 15) * 8;
            const float* srcm = io + (size_t)(row0 + m) * D + k8;
            float4 a = reinterpret_cast<const float4*>(srcm)[0];
            float4 b = reinterpret_cast<const float4*>(srcm)[1];
            uint4 o;
            o.x = pack2(a.x, a.y); o.y = pack2(a.z, a.w);
            o.z = pack2(b.x, b.y); o.w = pack2(b.z, b.w);
            const u32 byte = ((u32)(m * 512 + k8 * 2)) ^ ((u32)(m & 7) << 4);
            *reinterpret_cast<uint4*>(reinterpret_cast<char*>(As) + byte) = o;

            const float* srcx = x + (size_t)(row0 + m) * D + k8;
            a = reinterpret_cast<const float4*>(srcx)[0];
            b = reinterpret_cast<const float4*>(srcx)[1];
            o.x = pack2(a.x, a.y); o.y = pack2(a.z, a.w);
            o.z = pack2(b.x, b.y); o.w = pack2(b.z, b.w);
            const u32 byte2 = ((u32)(m * 512 + (128 + k8) * 2)) ^ ((u32)(m & 7) << 4);
            *reinterpret_cast<uint4*>(reinterpret_cast<char*>(As) + byte2) = o;
        }
        __syncthreads();

        f32x4 acc0 = {0.f, 0.f, 0.f, 0.f};
        f32x4 acc1 = {0.f, 0.f, 0.f, 0.f};
        const int j0 = wv * 32 + m16;
        const int j1 = j0 + 16;
        #pragma unroll
        for (int ks = 0; ks < 8; ks++) {
            const int k = ks * 32 + kg * 8;
            const u32 ab  = ((u32)(m16 * 512 + k * 2)) ^ ((u32)(m16 & 7) << 4);
            const u32 bb0 = ((u32)(j0  * 512 + k * 2)) ^ ((u32)(j0  & 7) << 4);
            const u32 bb1 = ((u32)(j1  * 512 + k * 2)) ^ ((u32)(j1  & 7) << 4);
            const short8 af  = *reinterpret_cast<const short8*>(reinterpret_cast<const char*>(As) + ab);
            const short8 bf0 = *reinterpret_cast<const short8*>(reinterpret_cast<const char*>(Bs) + bb0);
            const short8 bf1 = *reinterpret_cast<const short8*>(reinterpret_cast<const char*>(Bs) + bb1);
            acc0 = __builtin_amdgcn_mfma_f32_16x16x32_bf16(af, bf0, acc0, 0, 0, 0);
            acc1 = __builtin_amdgcn_mfma_f32_16x16x32_bf16(af, bf1, acc1, 0, 0, 0);
        }

        const float bias0 = bl[wv * 32 + m16];
        const float bias1 = bl[wv * 32 + 16 + m16];
        #pragma unroll
        for (int i = 0; i < 4; i++) {
            const int r = kg * 4 + i;
            float* orow = io + (size_t)(row0 + r) * D;
            orow[wv * 32 + m16]      = fmaxf(acc0[i] + bias0, 0.f);
            orow[wv * 32 + 16 + m16] = fmaxf(acc1[i] + bias1, 0.f);
        }
    }
}

// ---------------------------------------------------------------------------
extern "C" void kernel_launch(void* const* d_in, const int* in_sizes, int n_in,
                              void* d_out, int out_size, void* d_ws, size_t ws_size,
                              hipStream_t stream) {
    const float* x  = (const float*)d_in[0];
    const int*   ei = (const int*)  d_in[1];
    const float* Wl = (const float*)d_in[2];
    const float* bl = (const float*)d_in[3];
    const float* Wr = (const float*)d_in[4];

    char* ws = (char*)d_ws;
    u32*   dcnt = (u32*)(ws + DCNT_OFF);
    int*   flag = (int*)(ws + FLAG_OFF);
    u32*   head = (u32*)(ws + HEAD_OFF);
    u64*   node = (u64*)(ws + NODE_OFF);
    u32*   xf8  = (u32*)(ws + XF8_OFF);
    float* out  = (float*)d_out;

    hipMemsetAsync(dcnt, 0, 200064, stream);   // dcnt + flag; head needs no init
    k_detect<<<1, 256, 0, stream>>>(ei, flag);
    k_cast  <<<2048, 256, 0, stream>>>(x, (uint2*)xf8);
    k_link  <<<4096, 256, 0, stream>>>(ei, flag, dcnt, head, node);
    k_gather<<<(NN + 3) / 4, 256, 0, stream>>>(xf8, node, head, dcnt, out);
    k_gemm  <<<1024, 256, 0, stream>>>(Wl, Wr, bl, x, out);
}